// Round 6
// baseline (260.153 us; speedup 1.0000x reference)
//
#include <hip/hip_runtime.h>
#include <hip/hip_bf16.h>

typedef unsigned short u16;
typedef __attribute__((ext_vector_type(8))) __bf16 bf16x8;
typedef __attribute__((ext_vector_type(4))) float f32x4;

#define AS1 __attribute__((address_space(1)))
#define AS3 __attribute__((address_space(3)))

__device__ inline void gload_lds16(const void* g, void* l) {
  __builtin_amdgcn_global_load_lds((const AS1 void*)g, (AS3 void*)l, 16, 0, 0);
}

__device__ inline u16 f2bf(float f) {
  __bf16 h = (__bf16)f;
  return __builtin_bit_cast(u16, h);
}

// ---------------- fused weight transpose + bf16 convert ----------------
// W1 [512][256] -> w1t [256][512]; W2 [256][256] -> w2t [256][256];
// W3 [256][64]  -> w3t [64][256]   (w3t[n][k] = W3[k][n])
__global__ void conv_weights(const float* __restrict__ W1, const float* __restrict__ W2,
                             const float* __restrict__ W3, u16* __restrict__ w1t,
                             u16* __restrict__ w2t, u16* __restrict__ w3t) {
  int e = blockIdx.x * 256 + threadIdx.x;          // 0 .. 212991
  if (e < 131072) {
    int h = e >> 9, f = e & 511;
    w1t[e] = f2bf(W1[f * 256 + h]);
  } else if (e < 196608) {
    int x = e - 131072;
    int n = x >> 8, k = x & 255;
    w2t[x] = f2bf(W2[k * 256 + n]);
  } else if (e < 212992) {
    int x = e - 196608;
    int n = x >> 8, k = x & 255;
    w3t[x] = f2bf(W3[k * 64 + n]);
  }
}

// ================= fused topk + gemm1 mega-kernel =================
// 2560 blocks: bid%5==4 -> gemm1 block bid/5 (512); else topk row
// (bid/5)*4 + bid%5 (2048). 4:1 mix keeps HBM streaming and MFMA overlapped.

// ---- topk body: 2-deep pipelined scan + static-threshold compact ----
// uniform [0,1): 32nd largest of 65536 ~0.9995; T0=0.997 -> ~196 cands
// (P(<32) ~ 1e-119). Tail is wave-0 only, barrier-free.
// Tie-break (val desc, idx asc) == jax.lax.top_k.
__device__ void topk_body(int b, int t, const float* __restrict__ ppr,
                          float* __restrict__ tv, int* __restrict__ ti,
                          float* __restrict__ rs, char* smem) {
  float* cvals   = (float*)smem;            // 2048 f
  int*   cidx    = (int*)(smem + 8192);     // 2048 i
  float* partial = (float*)(smem + 16384);  // 4 f
  int*   cnt     = (int*)(smem + 16400);    // 1 i
  int*   sel     = (int*)(smem + 16416);    // 32 i (fallback only)
  const int lane = t & 63, w = t >> 6;
  const float* row = ppr + (size_t)b * 65536;
  const float4* rp = (const float4*)row;    // 16384 float4
  const float T0 = 0.997f;

  if (t == 0) *cnt = 0;
  __syncthreads();

  float sum = 0.f;
  float4 c0 = rp[t], c1 = rp[t + 256], c2 = rp[t + 512], c3 = rp[t + 768];

  auto consume = [&](int it) {
    float4 cs[4] = {c0, c1, c2, c3};
#pragma unroll
    for (int q = 0; q < 4; ++q) {
      float4 v = cs[q];
      sum += (v.x + v.y) + (v.z + v.w);
      float mx = fmaxf(fmaxf(v.x, v.y), fmaxf(v.z, v.w));
      if (mx > T0) {
        int fb = (it * 1024 + q * 256 + t) * 4;
        float xs[4] = {v.x, v.y, v.z, v.w};
#pragma unroll
        for (int j = 0; j < 4; ++j) {
          if (xs[j] > T0) {
            int p = atomicAdd(cnt, 1);
            if (p < 2048) { cvals[p] = xs[j]; cidx[p] = fb + j; }
          }
        }
      }
    }
  };

  for (int it = 0; it < 15; ++it) {
    int nb = (it + 1) * 1024 + t;
    float4 n0 = rp[nb], n1 = rp[nb + 256], n2 = rp[nb + 512], n3 = rp[nb + 768];
    consume(it);
    c0 = n0; c1 = n1; c2 = n2; c3 = n3;
  }
  consume(15);

#pragma unroll
  for (int off = 32; off > 0; off >>= 1) sum += __shfl_down(sum, off);
  if (lane == 0) partial[w] = sum;
  __syncthreads();

  if (w != 0) return;            // waves 1..3 done; no barriers below

  if (lane == 0) rs[b] = partial[0] + partial[1] + partial[2] + partial[3];
  int n = *cnt; n = n < 2048 ? n : 2048;

  if (n >= 32) {
    for (int r = 0; r < 32; ++r) {
      float bv = -__builtin_inff();
      int bi = 0x7fffffff, bp = -1;
      for (int p = lane; p < n; p += 64) {
        float xv = cvals[p];
        int xi = cidx[p];
        if (xv > bv || (xv == bv && xi < bi)) { bv = xv; bi = xi; bp = p; }
      }
#pragma unroll
      for (int off = 32; off > 0; off >>= 1) {
        float ov = __shfl_down(bv, off);
        int   oi = __shfl_down(bi, off);
        int   op = __shfl_down(bp, off);
        if (ov > bv || (ov == bv && oi < bi)) { bv = ov; bi = oi; bp = op; }
      }
      if (lane == 0) {
        tv[b * 32 + r] = bv;
        ti[b * 32 + r] = bi;
        if (bp >= 0) { cvals[bp] = -__builtin_inff(); cidx[bp] = 0x7fffffff; }
      }
    }
  } else {
    // exact fallback (never taken for uniform data)
    for (int r = 0; r < 32; ++r) {
      float bv = -__builtin_inff();
      int bi = 0x7fffffff;
      for (int p = lane; p < 65536; p += 64) {
        float xv = row[p];
        bool skip = false;
        for (int q = 0; q < r; ++q) skip = skip || (sel[q] == p);
        if (!skip && (xv > bv || (xv == bv && p < bi))) { bv = xv; bi = p; }
      }
#pragma unroll
      for (int off = 32; off > 0; off >>= 1) {
        float ov = __shfl_down(bv, off);
        int   oi = __shfl_down(bi, off);
        if (ov > bv || (ov == bv && oi < bi)) { bv = ov; bi = oi; }
      }
      if (lane == 0) { tv[b * 32 + r] = bv; ti[b * 32 + r] = bi; sel[r] = bi; }
    }
  }
}

// ---- gemm1 body: h1 = relu(X @ W1), BM=128 BN=256 (X read ONCE) ----
// waves 2x2: wave(wr,wc) owns rows wr*64, cols wc*128. acc[4][8] f32x4.
__device__ void gemm1_body(int bm, int t, const float* __restrict__ X,
                           const u16* __restrict__ Bt, u16* __restrict__ H,
                           char* smem) {
  constexpr int K = 512;
  u16* As = (u16*)smem;              // [128][32] bf16, 8 KB
  u16* Bs = (u16*)(smem + 8192);     // [256][32] bf16, 16 KB
  const int wid = t >> 6, lane = t & 63;
  const int wr = wid >> 1, wc = wid & 1;
  const int l15 = lane & 15, lk = lane >> 4;
  f32x4 acc[4][8];
  const f32x4 z = {0.f, 0.f, 0.f, 0.f};
#pragma unroll
  for (int i = 0; i < 4; ++i)
#pragma unroll
    for (int j = 0; j < 8; ++j) acc[i][j] = z;

  for (int k0 = 0; k0 < K; k0 += 32) {
#pragma unroll
    for (int it = 0; it < 4; ++it) {          // B tile [256][32]
      int s = it * 256 + t;
      const u16* src = Bt + (size_t)(s >> 2) * K + k0 + (s & 3) * 8;
      gload_lds16(src, &Bs[(it * 256 + wid * 64) * 8]);
    }
#pragma unroll
    for (int it = 0; it < 2; ++it) {          // A tile [128][32], fp32->bf16
      int s = it * 256 + t;
      const float* src = X + (size_t)(bm * 128 + (s >> 2)) * K + k0 + (s & 3) * 8;
      float4 v0 = *(const float4*)src;
      float4 v1 = *(const float4*)(src + 4);
      bf16x8 wv;
      wv[0] = (__bf16)v0.x; wv[1] = (__bf16)v0.y; wv[2] = (__bf16)v0.z; wv[3] = (__bf16)v0.w;
      wv[4] = (__bf16)v1.x; wv[5] = (__bf16)v1.y; wv[6] = (__bf16)v1.z; wv[7] = (__bf16)v1.w;
      *(bf16x8*)&As[s * 8] = wv;
    }
    __syncthreads();
    bf16x8 af[4], bfr[8];
#pragma unroll
    for (int i = 0; i < 4; ++i)
      af[i] = *(const bf16x8*)&As[(wr * 64 + i * 16 + l15) * 32 + lk * 8];
#pragma unroll
    for (int j = 0; j < 8; ++j)
      bfr[j] = *(const bf16x8*)&Bs[(wc * 128 + j * 16 + l15) * 32 + lk * 8];
#pragma unroll
    for (int i = 0; i < 4; ++i)
#pragma unroll
      for (int j = 0; j < 8; ++j)
        acc[i][j] = __builtin_amdgcn_mfma_f32_16x16x32_bf16(af[i], bfr[j], acc[i][j], 0, 0, 0);
    __syncthreads();
  }
  // staged coalesced store: col-half h staged as [128][136] u16 then dwordx4 rows
  u16* stage = (u16*)smem;
#pragma unroll
  for (int h = 0; h < 2; ++h) {
    __syncthreads();
    if (wc == h) {
#pragma unroll
      for (int i = 0; i < 4; ++i)
#pragma unroll
        for (int j = 0; j < 8; ++j)
#pragma unroll
          for (int r = 0; r < 4; ++r)
            stage[(wr * 64 + i * 16 + lk * 4 + r) * 136 + j * 16 + l15] =
                f2bf(fmaxf(acc[i][j][r], 0.f));
    }
    __syncthreads();
#pragma unroll
    for (int q = 0; q < 8; ++q) {
      int row = q * 16 + (t >> 4), ch = t & 15;
      f32x4 d = *(const f32x4*)&stage[row * 136 + ch * 8];
      *(f32x4*)&H[(size_t)(bm * 128 + row) * 256 + h * 128 + ch * 8] = d;
    }
  }
}

__global__ __launch_bounds__(256, 2) void mega1(const float* __restrict__ ppr,
                                                float* __restrict__ tv, int* __restrict__ ti,
                                                float* __restrict__ rs,
                                                const float* __restrict__ X,
                                                const u16* __restrict__ Bt,
                                                u16* __restrict__ H) {
  __shared__ alignas(16) char smem[34816];
  const int bid = blockIdx.x;
  const int role = bid % 5, g = bid / 5;
  const int t = threadIdx.x;
  if (role == 4) gemm1_body(g, t, X, Bt, H, smem);
  else           topk_body(g * 4 + role, t, ppr, tv, ti, rs, smem);
}

// ================= fused gemm2+gemm3: lg = relu(h1@W2) @ W3 =================
// 512 blocks, rows bm*128. Stage 1: h2row [128x256] in regs (2x2 waves,
// acc1[4][8]). Stage 2: per 64-col quadrant kk, owner waves dump relu'd bf16
// into XOR-swizzled LDS quad [128][64] (G4: linear [row][64] would be 16-way
// bank conflict), W3 chunk staged via gload_lds with pre-swizzled SOURCE
// (m173: LDS dst is linear), then all waves MFMA: acc2[2][4] over rows w*32.
__global__ __launch_bounds__(256, 2) void gemm23_kernel(const u16* __restrict__ A,
                                                        const u16* __restrict__ Bt,
                                                        const u16* __restrict__ W3t,
                                                        float* __restrict__ lg) {
  __shared__ alignas(16) char smem[49152];
  u16* As   = (u16*)smem;                 // [128][32]  8 KB
  u16* Bs   = (u16*)(smem + 8192);        // [256][32] 16 KB
  u16* quad = (u16*)(smem + 24576);       // [128][64] swizzled, 16 KB
  u16* w3s  = (u16*)(smem + 40960);       // [64][64]  swizzled, 8 KB
  constexpr int K = 256;
  const int bm = blockIdx.x, t = threadIdx.x;
  const int wid = t >> 6, lane = t & 63;
  const int wr = wid >> 1, wc = wid & 1;
  const int l15 = lane & 15, lk = lane >> 4;

  f32x4 acc1[4][8];
  f32x4 acc2[2][4];
  const f32x4 z = {0.f, 0.f, 0.f, 0.f};
#pragma unroll
  for (int i = 0; i < 4; ++i)
#pragma unroll
    for (int j = 0; j < 8; ++j) acc1[i][j] = z;
#pragma unroll
  for (int i = 0; i < 2; ++i)
#pragma unroll
    for (int j = 0; j < 4; ++j) acc2[i][j] = z;

  // ---- stage 1: h2row = relu(h1[bm] @ W2) in registers ----
  for (int k0 = 0; k0 < K; k0 += 32) {
#pragma unroll
    for (int it = 0; it < 4; ++it) {
      int s = it * 256 + t;
      const u16* src = Bt + (size_t)(s >> 2) * K + k0 + (s & 3) * 8;
      gload_lds16(src, &Bs[(it * 256 + wid * 64) * 8]);
    }
#pragma unroll
    for (int it = 0; it < 2; ++it) {
      int s = it * 256 + t;
      const u16* src = A + (size_t)(bm * 128 + (s >> 2)) * K + k0 + (s & 3) * 8;
      gload_lds16(src, &As[(it * 256 + wid * 64) * 8]);
    }
    __syncthreads();
    bf16x8 af[4], bfr[8];
#pragma unroll
    for (int i = 0; i < 4; ++i)
      af[i] = *(const bf16x8*)&As[(wr * 64 + i * 16 + l15) * 32 + lk * 8];
#pragma unroll
    for (int j = 0; j < 8; ++j)
      bfr[j] = *(const bf16x8*)&Bs[(wc * 128 + j * 16 + l15) * 32 + lk * 8];
#pragma unroll
    for (int i = 0; i < 4; ++i)
#pragma unroll
      for (int j = 0; j < 8; ++j)
        acc1[i][j] = __builtin_amdgcn_mfma_f32_16x16x32_bf16(af[i], bfr[j], acc1[i][j], 0, 0, 0);
    __syncthreads();
  }

  // ---- stage 2: lg[128x64] += relu(h2)[:,kk*64..] @ W3[kk*64..,:] ----
#pragma unroll
  for (int kk = 0; kk < 4; ++kk) {
    // owner waves (wc == kk>>1) dump their relu'd quadrant, swizzled
    if (wc == (kk >> 1)) {
#pragma unroll
      for (int i = 0; i < 4; ++i)
#pragma unroll
        for (int j4 = 0; j4 < 4; ++j4) {
          int j = (kk & 1) * 4 + j4;
#pragma unroll
          for (int r = 0; r < 4; ++r) {
            int row = wr * 64 + i * 16 + lk * 4 + r;
            int c   = j4 * 16 + l15;
            quad[(row * 64 + c) ^ ((row & 7) << 3)] = f2bf(fmaxf(acc1[i][j][r], 0.f));
          }
        }
    }
    // stage W3 chunk [64 cols][k=kk*64..+64] with pre-swizzled source so the
    // swizzled read below sees W3t[col][kk*64+k]. dst chunk s <- source
    // k-offset ((s ^ (col&7)) & 7)*8.
#pragma unroll
    for (int it = 0; it < 2; ++it) {
      int s = it * 256 + t;
      int col = s >> 3;
      int koff = ((s ^ (col & 7)) & 7) * 8;
      const u16* src = W3t + (size_t)col * 256 + kk * 64 + koff;
      gload_lds16(src, &w3s[(it * 256 + wid * 64) * 8]);
    }
    __syncthreads();
    bf16x8 af2, bfr2[4];
#pragma unroll
    for (int ks = 0; ks < 2; ++ks) {
#pragma unroll
      for (int j2 = 0; j2 < 4; ++j2) {
        int col = j2 * 16 + l15;
        bfr2[j2] = *(const bf16x8*)&w3s[(col * 64 + ks * 32 + lk * 8) ^ ((col & 7) << 3)];
      }
#pragma unroll
      for (int i2 = 0; i2 < 2; ++i2) {
        int row = wid * 32 + i2 * 16 + l15;
        af2 = *(const bf16x8*)&quad[(row * 64 + ks * 32 + lk * 8) ^ ((row & 7) << 3)];
#pragma unroll
        for (int j2 = 0; j2 < 4; ++j2)
          acc2[i2][j2] = __builtin_amdgcn_mfma_f32_16x16x32_bf16(af2, bfr2[j2], acc2[i2][j2], 0, 0, 0);
      }
    }
    __syncthreads();
  }

  // epilogue: wave w owns rows w*32..+32, cols 0..63
#pragma unroll
  for (int i2 = 0; i2 < 2; ++i2)
#pragma unroll
    for (int j2 = 0; j2 < 4; ++j2) {
      int col = j2 * 16 + l15;
#pragma unroll
      for (int r = 0; r < 4; ++r) {
        int row = wid * 32 + i2 * 16 + lk * 4 + r;
        lg[(size_t)(bm * 128 + row) * 64 + col] = acc2[i2][j2][r];
      }
    }
}

// ---------------- soft-k-medoid per row ----------------
__global__ __launch_bounds__(256) void medoid_kernel(const float* __restrict__ logits,
                                                     const float* __restrict__ tv,
                                                     const int* __restrict__ ti,
                                                     const float* __restrict__ rs,
                                                     float* __restrict__ out) {
  __shared__ float xk[32 * 65];
  __shared__ float l2m[32 * 33];
  __shared__ float vals[32];
  __shared__ int   idxs[32];
  __shared__ float dist[32];
  __shared__ float w[32];
  const int b = blockIdx.x, t = threadIdx.x;
  if (t < 32) { vals[t] = tv[b * 32 + t]; idxs[t] = ti[b * 32 + t]; }
  __syncthreads();
#pragma unroll
  for (int j = 0; j < 8; ++j) {
    int s = j * 256 + t;
    int r = s >> 6, c = s & 63;
    xk[r * 65 + c] = logits[(size_t)idxs[r] * 64 + c];
  }
  __syncthreads();
#pragma unroll
  for (int j = 0; j < 4; ++j) {
    int p = j * 256 + t;
    int c = p >> 5, m = p & 31;
    float d = 0.f;
#pragma unroll
    for (int ch = 0; ch < 64; ++ch) {
      float df = xk[c * 65 + ch] - xk[m * 65 + ch];
      d += df * df;
    }
    l2m[c * 33 + m] = sqrtf(d + 1e-12f);
  }
  __syncthreads();
  if (t < 32) {
    float d = 0.f;
#pragma unroll
    for (int m = 0; m < 32; ++m) d += vals[m] * l2m[t * 33 + m];
    if (vals[t] == 0.f) d = 3.402823466e+38f;
    dist[t] = d;
  }
  __syncthreads();
  if (t == 0) {
    float mx = -3.402823466e+38f;
    for (int c = 0; c < 32; ++c) mx = fmaxf(mx, -dist[c]);
    float s = 0.f;
    for (int c = 0; c < 32; ++c) { float e = expf(-dist[c] - mx); w[c] = e; s += e; }
    float s2 = 0.f;
    for (int c = 0; c < 32; ++c) { w[c] = w[c] / s * vals[c]; s2 += w[c]; }
    float inv = 1.f / s2;
    for (int c = 0; c < 32; ++c) w[c] *= inv;
  }
  __syncthreads();
  if (t < 64) {
    float o = 0.f;
#pragma unroll
    for (int k = 0; k < 32; ++k) o += w[k] * xk[k * 65 + t];
    out[(size_t)b * 64 + t] = rs[b] * o;
  }
}

// ---------------- launch ----------------
extern "C" void kernel_launch(void* const* d_in, const int* in_sizes, int n_in,
                              void* d_out, int out_size, void* d_ws, size_t ws_size,
                              hipStream_t stream) {
  const float* X   = (const float*)d_in[0];
  const float* ppr = (const float*)d_in[1];
  const float* W1  = (const float*)d_in[2];
  const float* W2  = (const float*)d_in[3];
  const float* W3  = (const float*)d_in[4];
  float* out = (float*)d_out;
  char* ws = (char*)d_ws;

  u16*  w1t = (u16*)(ws + 0);                    // 256x512 bf16
  u16*  w2t = (u16*)(ws + 262144);               // 256x256 bf16
  u16*  w3t = (u16*)(ws + 393216);               // 64x256 bf16
  u16*  h1  = (u16*)(ws + 458752);               // 65536x256 bf16
  float* lg = (float*)(ws + 34013184);           // 65536x64 fp32
  float* tv = (float*)(ws + 50790400);           // 2048x32
  int*   ti = (int*)(ws + 51052544);             // 2048x32
  float* rs = (float*)(ws + 51314688);           // 2048

  (void)in_sizes; (void)n_in; (void)out_size; (void)ws_size;

  conv_weights<<<832, 256, 0, stream>>>(W1, W2, W3, w1t, w2t, w3t);
  mega1<<<2560, 256, 0, stream>>>(ppr, tv, ti, rs, X, w1t, h1);
  gemm23_kernel<<<512, 256, 0, stream>>>(h1, w2t, w3t, lg);
  medoid_kernel<<<2048, 256, 0, stream>>>(lg, tv, ti, rs, out);
}

// Round 7
// 260.121 us; speedup vs baseline: 1.0001x; 1.0001x over previous
//
#include <hip/hip_runtime.h>
#include <hip/hip_bf16.h>

typedef unsigned short u16;
typedef __attribute__((ext_vector_type(8))) __bf16 bf16x8;
typedef __attribute__((ext_vector_type(4))) float f32x4;

#define AS1 __attribute__((address_space(1)))
#define AS3 __attribute__((address_space(3)))

__device__ inline void gload_lds16(const void* g, void* l) {
  __builtin_amdgcn_global_load_lds((const AS1 void*)g, (AS3 void*)l, 16, 0, 0);
}

__device__ inline u16 f2bf(float f) {
  __bf16 h = (__bf16)f;
  return __builtin_bit_cast(u16, h);
}

// ---------------- fused weight transpose + bf16 convert ----------------
// W1 [512][256] -> w1t [256][512]; W2 [256][256] -> w2t [256][256];
// W3 [256][64]  -> w3t [64][256]   (w3t[n][k] = W3[k][n])
__global__ void conv_weights(const float* __restrict__ W1, const float* __restrict__ W2,
                             const float* __restrict__ W3, u16* __restrict__ w1t,
                             u16* __restrict__ w2t, u16* __restrict__ w3t) {
  int e = blockIdx.x * 256 + threadIdx.x;          // 0 .. 212991
  if (e < 131072) {
    int h = e >> 9, f = e & 511;
    w1t[e] = f2bf(W1[f * 256 + h]);
  } else if (e < 196608) {
    int x = e - 131072;
    int n = x >> 8, k = x & 255;
    w2t[x] = f2bf(W2[k * 256 + n]);
  } else if (e < 212992) {
    int x = e - 196608;
    int n = x >> 8, k = x & 255;
    w3t[x] = f2bf(W3[k * 64 + n]);
  }
}

// ================= fused topk + gemm1 mega-kernel =================
// 2560 blocks: bid%5==4 -> gemm1 block bid/5 (512); else topk row
// (bid/5)*4 + bid%5 (2048). 4:1 mix keeps HBM streaming and MFMA overlapped.

// ---- topk body: 2-deep pipelined scan + static-threshold compact ----
// uniform [0,1): 32nd largest of 65536 ~0.9995; T0=0.997 -> ~196 cands
// (P(<32) ~ 1e-119). Tail is wave-0 only, barrier-free.
// Tie-break (val desc, idx asc) == jax.lax.top_k.
__device__ void topk_body(int b, int t, const float* __restrict__ ppr,
                          float* __restrict__ tv, int* __restrict__ ti,
                          float* __restrict__ rs, char* smem) {
  float* cvals   = (float*)smem;            // 2048 f
  int*   cidx    = (int*)(smem + 8192);     // 2048 i
  float* partial = (float*)(smem + 16384);  // 4 f
  int*   cnt     = (int*)(smem + 16400);    // 1 i
  int*   sel     = (int*)(smem + 16416);    // 32 i (fallback only)
  const int lane = t & 63, w = t >> 6;
  const float* row = ppr + (size_t)b * 65536;
  const float4* rp = (const float4*)row;    // 16384 float4
  const float T0 = 0.997f;

  if (t == 0) *cnt = 0;
  __syncthreads();

  float sum = 0.f;
  float4 c0 = rp[t], c1 = rp[t + 256], c2 = rp[t + 512], c3 = rp[t + 768];

  auto consume = [&](int it) {
    float4 cs[4] = {c0, c1, c2, c3};
#pragma unroll
    for (int q = 0; q < 4; ++q) {
      float4 v = cs[q];
      sum += (v.x + v.y) + (v.z + v.w);
      float mx = fmaxf(fmaxf(v.x, v.y), fmaxf(v.z, v.w));
      if (mx > T0) {
        int fb = (it * 1024 + q * 256 + t) * 4;
        float xs[4] = {v.x, v.y, v.z, v.w};
#pragma unroll
        for (int j = 0; j < 4; ++j) {
          if (xs[j] > T0) {
            int p = atomicAdd(cnt, 1);
            if (p < 2048) { cvals[p] = xs[j]; cidx[p] = fb + j; }
          }
        }
      }
    }
  };

  for (int it = 0; it < 15; ++it) {
    int nb = (it + 1) * 1024 + t;
    float4 n0 = rp[nb], n1 = rp[nb + 256], n2 = rp[nb + 512], n3 = rp[nb + 768];
    consume(it);
    c0 = n0; c1 = n1; c2 = n2; c3 = n3;
  }
  consume(15);

#pragma unroll
  for (int off = 32; off > 0; off >>= 1) sum += __shfl_down(sum, off);
  if (lane == 0) partial[w] = sum;
  __syncthreads();

  if (w != 0) return;            // waves 1..3 done; no barriers below

  if (lane == 0) rs[b] = partial[0] + partial[1] + partial[2] + partial[3];
  int n = *cnt; n = n < 2048 ? n : 2048;

  if (n >= 32) {
    for (int r = 0; r < 32; ++r) {
      float bv = -__builtin_inff();
      int bi = 0x7fffffff, bp = -1;
      for (int p = lane; p < n; p += 64) {
        float xv = cvals[p];
        int xi = cidx[p];
        if (xv > bv || (xv == bv && xi < bi)) { bv = xv; bi = xi; bp = p; }
      }
#pragma unroll
      for (int off = 32; off > 0; off >>= 1) {
        float ov = __shfl_down(bv, off);
        int   oi = __shfl_down(bi, off);
        int   op = __shfl_down(bp, off);
        if (ov > bv || (ov == bv && oi < bi)) { bv = ov; bi = oi; bp = op; }
      }
      if (lane == 0) {
        tv[b * 32 + r] = bv;
        ti[b * 32 + r] = bi;
        if (bp >= 0) { cvals[bp] = -__builtin_inff(); cidx[bp] = 0x7fffffff; }
      }
    }
  } else {
    // exact fallback (never taken for uniform data)
    for (int r = 0; r < 32; ++r) {
      float bv = -__builtin_inff();
      int bi = 0x7fffffff;
      for (int p = lane; p < 65536; p += 64) {
        float xv = row[p];
        bool skip = false;
        for (int q = 0; q < r; ++q) skip = skip || (sel[q] == p);
        if (!skip && (xv > bv || (xv == bv && p < bi))) { bv = xv; bi = p; }
      }
#pragma unroll
      for (int off = 32; off > 0; off >>= 1) {
        float ov = __shfl_down(bv, off);
        int   oi = __shfl_down(bi, off);
        if (ov > bv || (ov == bv && oi < bi)) { bv = ov; bi = oi; }
      }
      if (lane == 0) { tv[b * 32 + r] = bv; ti[b * 32 + r] = bi; sel[r] = bi; }
    }
  }
}

// ---- gemm1 body: h1 = relu(X @ W1), BM=128 BN=256 (X read ONCE) ----
// waves 2x2: wave(wr,wc) owns rows wr*64, cols wc*128. acc[4][8] f32x4.
__device__ void gemm1_body(int bm, int t, const float* __restrict__ X,
                           const u16* __restrict__ Bt, u16* __restrict__ H,
                           char* smem) {
  constexpr int K = 512;
  u16* As = (u16*)smem;              // [128][32] bf16, 8 KB
  u16* Bs = (u16*)(smem + 8192);     // [256][32] bf16, 16 KB
  const int wid = t >> 6, lane = t & 63;
  const int wr = wid >> 1, wc = wid & 1;
  const int l15 = lane & 15, lk = lane >> 4;
  f32x4 acc[4][8];
  const f32x4 z = {0.f, 0.f, 0.f, 0.f};
#pragma unroll
  for (int i = 0; i < 4; ++i)
#pragma unroll
    for (int j = 0; j < 8; ++j) acc[i][j] = z;

  for (int k0 = 0; k0 < K; k0 += 32) {
#pragma unroll
    for (int it = 0; it < 4; ++it) {          // B tile [256][32]
      int s = it * 256 + t;
      const u16* src = Bt + (size_t)(s >> 2) * K + k0 + (s & 3) * 8;
      gload_lds16(src, &Bs[(it * 256 + wid * 64) * 8]);
    }
#pragma unroll
    for (int it = 0; it < 2; ++it) {          // A tile [128][32], fp32->bf16
      int s = it * 256 + t;
      const float* src = X + (size_t)(bm * 128 + (s >> 2)) * K + k0 + (s & 3) * 8;
      float4 v0 = *(const float4*)src;
      float4 v1 = *(const float4*)(src + 4);
      bf16x8 wv;
      wv[0] = (__bf16)v0.x; wv[1] = (__bf16)v0.y; wv[2] = (__bf16)v0.z; wv[3] = (__bf16)v0.w;
      wv[4] = (__bf16)v1.x; wv[5] = (__bf16)v1.y; wv[6] = (__bf16)v1.z; wv[7] = (__bf16)v1.w;
      *(bf16x8*)&As[s * 8] = wv;
    }
    __syncthreads();
    bf16x8 af[4], bfr[8];
#pragma unroll
    for (int i = 0; i < 4; ++i)
      af[i] = *(const bf16x8*)&As[(wr * 64 + i * 16 + l15) * 32 + lk * 8];
#pragma unroll
    for (int j = 0; j < 8; ++j)
      bfr[j] = *(const bf16x8*)&Bs[(wc * 128 + j * 16 + l15) * 32 + lk * 8];
#pragma unroll
    for (int i = 0; i < 4; ++i)
#pragma unroll
      for (int j = 0; j < 8; ++j)
        acc[i][j] = __builtin_amdgcn_mfma_f32_16x16x32_bf16(af[i], bfr[j], acc[i][j], 0, 0, 0);
    __syncthreads();
  }
  // staged coalesced store: col-half h staged as [128][136] u16 then dwordx4 rows
  u16* stage = (u16*)smem;
#pragma unroll
  for (int h = 0; h < 2; ++h) {
    __syncthreads();
    if (wc == h) {
#pragma unroll
      for (int i = 0; i < 4; ++i)
#pragma unroll
        for (int j = 0; j < 8; ++j)
#pragma unroll
          for (int r = 0; r < 4; ++r)
            stage[(wr * 64 + i * 16 + lk * 4 + r) * 136 + j * 16 + l15] =
                f2bf(fmaxf(acc[i][j][r], 0.f));
    }
    __syncthreads();
#pragma unroll
    for (int q = 0; q < 8; ++q) {
      int row = q * 16 + (t >> 4), ch = t & 15;
      f32x4 d = *(const f32x4*)&stage[row * 136 + ch * 8];
      *(f32x4*)&H[(size_t)(bm * 128 + row) * 256 + h * 128 + ch * 8] = d;
    }
  }
}

__global__ __launch_bounds__(256, 2) void mega1(const float* __restrict__ ppr,
                                                float* __restrict__ tv, int* __restrict__ ti,
                                                float* __restrict__ rs,
                                                const float* __restrict__ X,
                                                const u16* __restrict__ Bt,
                                                u16* __restrict__ H) {
  __shared__ alignas(16) char smem[34816];
  const int bid = blockIdx.x;
  const int role = bid % 5, g = bid / 5;
  const int t = threadIdx.x;
  if (role == 4) gemm1_body(g, t, X, Bt, H, smem);
  else           topk_body(g * 4 + role, t, ppr, tv, ti, rs, smem);
}

// ================= fused gemm2+gemm3: lg = relu(h1@W2) @ W3 =================
// 512 blocks, rows bm*128. Stage 1: h2row [128x256] in regs (2x2 waves,
// acc1[4][8]). Stage 2: per 64-col quadrant kk, owner waves dump relu'd bf16
// into XOR-swizzled LDS quad [128][64] (G4: linear [row][64] would be 16-way
// bank conflict), W3 chunk staged via gload_lds with pre-swizzled SOURCE
// (m173: LDS dst is linear), then all waves MFMA: acc2[2][4] over rows w*32.
__global__ __launch_bounds__(256, 2) void gemm23_kernel(const u16* __restrict__ A,
                                                        const u16* __restrict__ Bt,
                                                        const u16* __restrict__ W3t,
                                                        float* __restrict__ lg) {
  __shared__ alignas(16) char smem[49152];
  u16* As   = (u16*)smem;                 // [128][32]  8 KB
  u16* Bs   = (u16*)(smem + 8192);        // [256][32] 16 KB
  u16* quad = (u16*)(smem + 24576);       // [128][64] swizzled, 16 KB
  u16* w3s  = (u16*)(smem + 40960);       // [64][64]  swizzled, 8 KB
  constexpr int K = 256;
  const int bm = blockIdx.x, t = threadIdx.x;
  const int wid = t >> 6, lane = t & 63;
  const int wr = wid >> 1, wc = wid & 1;
  const int l15 = lane & 15, lk = lane >> 4;

  f32x4 acc1[4][8];
  f32x4 acc2[2][4];
  const f32x4 z = {0.f, 0.f, 0.f, 0.f};
#pragma unroll
  for (int i = 0; i < 4; ++i)
#pragma unroll
    for (int j = 0; j < 8; ++j) acc1[i][j] = z;
#pragma unroll
  for (int i = 0; i < 2; ++i)
#pragma unroll
    for (int j = 0; j < 4; ++j) acc2[i][j] = z;

  // ---- stage 1: h2row = relu(h1[bm] @ W2) in registers ----
  for (int k0 = 0; k0 < K; k0 += 32) {
#pragma unroll
    for (int it = 0; it < 4; ++it) {
      int s = it * 256 + t;
      const u16* src = Bt + (size_t)(s >> 2) * K + k0 + (s & 3) * 8;
      gload_lds16(src, &Bs[(it * 256 + wid * 64) * 8]);
    }
#pragma unroll
    for (int it = 0; it < 2; ++it) {
      int s = it * 256 + t;
      const u16* src = A + (size_t)(bm * 128 + (s >> 2)) * K + k0 + (s & 3) * 8;
      gload_lds16(src, &As[(it * 256 + wid * 64) * 8]);
    }
    __syncthreads();
    bf16x8 af[4], bfr[8];
#pragma unroll
    for (int i = 0; i < 4; ++i)
      af[i] = *(const bf16x8*)&As[(wr * 64 + i * 16 + l15) * 32 + lk * 8];
#pragma unroll
    for (int j = 0; j < 8; ++j)
      bfr[j] = *(const bf16x8*)&Bs[(wc * 128 + j * 16 + l15) * 32 + lk * 8];
#pragma unroll
    for (int i = 0; i < 4; ++i)
#pragma unroll
      for (int j = 0; j < 8; ++j)
        acc1[i][j] = __builtin_amdgcn_mfma_f32_16x16x32_bf16(af[i], bfr[j], acc1[i][j], 0, 0, 0);
    __syncthreads();
  }

  // ---- stage 2: lg[128x64] += relu(h2)[:,kk*64..] @ W3[kk*64..,:] ----
#pragma unroll
  for (int kk = 0; kk < 4; ++kk) {
    // owner waves (wc == kk>>1) dump their relu'd quadrant, swizzled
    if (wc == (kk >> 1)) {
#pragma unroll
      for (int i = 0; i < 4; ++i)
#pragma unroll
        for (int j4 = 0; j4 < 4; ++j4) {
          int j = (kk & 1) * 4 + j4;
#pragma unroll
          for (int r = 0; r < 4; ++r) {
            int row = wr * 64 + i * 16 + lk * 4 + r;
            int c   = j4 * 16 + l15;
            quad[(row * 64 + c) ^ ((row & 7) << 3)] = f2bf(fmaxf(acc1[i][j][r], 0.f));
          }
        }
    }
    // stage W3 chunk [64 cols][k=kk*64..+64] with pre-swizzled source so the
    // swizzled read below sees W3t[col][kk*64+k]. dst chunk s <- source
    // k-offset ((s ^ (col&7)) & 7)*8.
#pragma unroll
    for (int it = 0; it < 2; ++it) {
      int s = it * 256 + t;
      int col = s >> 3;
      int koff = ((s ^ (col & 7)) & 7) * 8;
      const u16* src = W3t + (size_t)col * 256 + kk * 64 + koff;
      gload_lds16(src, &w3s[(it * 256 + wid * 64) * 8]);
    }
    __syncthreads();
    bf16x8 af2, bfr2[4];
#pragma unroll
    for (int ks = 0; ks < 2; ++ks) {
#pragma unroll
      for (int j2 = 0; j2 < 4; ++j2) {
        int col = j2 * 16 + l15;
        bfr2[j2] = *(const bf16x8*)&w3s[(col * 64 + ks * 32 + lk * 8) ^ ((col & 7) << 3)];
      }
#pragma unroll
      for (int i2 = 0; i2 < 2; ++i2) {
        int row = wid * 32 + i2 * 16 + l15;
        af2 = *(const bf16x8*)&quad[(row * 64 + ks * 32 + lk * 8) ^ ((row & 7) << 3)];
#pragma unroll
        for (int j2 = 0; j2 < 4; ++j2)
          acc2[i2][j2] = __builtin_amdgcn_mfma_f32_16x16x32_bf16(af2, bfr2[j2], acc2[i2][j2], 0, 0, 0);
      }
    }
    __syncthreads();
  }

  // epilogue: wave w owns rows w*32..+32, cols 0..63
#pragma unroll
  for (int i2 = 0; i2 < 2; ++i2)
#pragma unroll
    for (int j2 = 0; j2 < 4; ++j2) {
      int col = j2 * 16 + l15;
#pragma unroll
      for (int r = 0; r < 4; ++r) {
        int row = wid * 32 + i2 * 16 + lk * 4 + r;
        lg[(size_t)(bm * 128 + row) * 64 + col] = acc2[i2][j2][r];
      }
    }
}

// ---------------- soft-k-medoid per row ----------------
__global__ __launch_bounds__(256) void medoid_kernel(const float* __restrict__ logits,
                                                     const float* __restrict__ tv,
                                                     const int* __restrict__ ti,
                                                     const float* __restrict__ rs,
                                                     float* __restrict__ out) {
  __shared__ float xk[32 * 65];
  __shared__ float l2m[32 * 33];
  __shared__ float vals[32];
  __shared__ int   idxs[32];
  __shared__ float dist[32];
  __shared__ float w[32];
  const int b = blockIdx.x, t = threadIdx.x;
  if (t < 32) { vals[t] = tv[b * 32 + t]; idxs[t] = ti[b * 32 + t]; }
  __syncthreads();
#pragma unroll
  for (int j = 0; j < 8; ++j) {
    int s = j * 256 + t;
    int r = s >> 6, c = s & 63;
    xk[r * 65 + c] = logits[(size_t)idxs[r] * 64 + c];
  }
  __syncthreads();
#pragma unroll
  for (int j = 0; j < 4; ++j) {
    int p = j * 256 + t;
    int c = p >> 5, m = p & 31;
    float d = 0.f;
#pragma unroll
    for (int ch = 0; ch < 64; ++ch) {
      float df = xk[c * 65 + ch] - xk[m * 65 + ch];
      d += df * df;
    }
    l2m[c * 33 + m] = sqrtf(d + 1e-12f);
  }
  __syncthreads();
  if (t < 32) {
    float d = 0.f;
#pragma unroll
    for (int m = 0; m < 32; ++m) d += vals[m] * l2m[t * 33 + m];
    if (vals[t] == 0.f) d = 3.402823466e+38f;
    dist[t] = d;
  }
  __syncthreads();
  if (t == 0) {
    float mx = -3.402823466e+38f;
    for (int c = 0; c < 32; ++c) mx = fmaxf(mx, -dist[c]);
    float s = 0.f;
    for (int c = 0; c < 32; ++c) { float e = expf(-dist[c] - mx); w[c] = e; s += e; }
    float s2 = 0.f;
    for (int c = 0; c < 32; ++c) { w[c] = w[c] / s * vals[c]; s2 += w[c]; }
    float inv = 1.f / s2;
    for (int c = 0; c < 32; ++c) w[c] *= inv;
  }
  __syncthreads();
  if (t < 64) {
    float o = 0.f;
#pragma unroll
    for (int k = 0; k < 32; ++k) o += w[k] * xk[k * 65 + t];
    out[(size_t)b * 64 + t] = rs[b] * o;
  }
}

// ---------------- launch ----------------
extern "C" void kernel_launch(void* const* d_in, const int* in_sizes, int n_in,
                              void* d_out, int out_size, void* d_ws, size_t ws_size,
                              hipStream_t stream) {
  const float* X   = (const float*)d_in[0];
  const float* ppr = (const float*)d_in[1];
  const float* W1  = (const float*)d_in[2];
  const float* W2  = (const float*)d_in[3];
  const float* W3  = (const float*)d_in[4];
  float* out = (float*)d_out;
  char* ws = (char*)d_ws;

  u16*  w1t = (u16*)(ws + 0);                    // 256x512 bf16
  u16*  w2t = (u16*)(ws + 262144);               // 256x256 bf16
  u16*  w3t = (u16*)(ws + 393216);               // 64x256 bf16
  u16*  h1  = (u16*)(ws + 458752);               // 65536x256 bf16
  float* lg = (float*)(ws + 34013184);           // 65536x64 fp32
  float* tv = (float*)(ws + 50790400);           // 2048x32
  int*   ti = (int*)(ws + 51052544);             // 2048x32
  float* rs = (float*)(ws + 51314688);           // 2048

  (void)in_sizes; (void)n_in; (void)out_size; (void)ws_size;

  conv_weights<<<832, 256, 0, stream>>>(W1, W2, W3, w1t, w2t, w3t);
  mega1<<<2560, 256, 0, stream>>>(ppr, tv, ti, rs, X, w1t, h1);
  gemm23_kernel<<<512, 256, 0, stream>>>(h1, w2t, w3t, lg);
  medoid_kernel<<<2048, 256, 0, stream>>>(lg, tv, ti, rs, out);
}

// Round 8
// 218.525 us; speedup vs baseline: 1.1905x; 1.1903x over previous
//
#include <hip/hip_runtime.h>
#include <hip/hip_bf16.h>

typedef unsigned short u16;
typedef __attribute__((ext_vector_type(8))) __bf16 bf16x8;
typedef __attribute__((ext_vector_type(4))) float f32x4;

#define AS1 __attribute__((address_space(1)))
#define AS3 __attribute__((address_space(3)))

__device__ inline void gload_lds16(const void* g, void* l) {
  __builtin_amdgcn_global_load_lds((const AS1 void*)g, (AS3 void*)l, 16, 0, 0);
}

__device__ inline u16 f2bf(float f) {
  __bf16 h = (__bf16)f;
  return __builtin_bit_cast(u16, h);
}

// ---------------- fused weight transpose + bf16 convert ----------------
// W1 [512][256] -> w1t [256][512]; W2 [256][256] -> w2t [256][256];
// W3 [256][64]  -> w3t [64][256]   (w3t[n][k] = W3[k][n])
__global__ void conv_weights(const float* __restrict__ W1, const float* __restrict__ W2,
                             const float* __restrict__ W3, u16* __restrict__ w1t,
                             u16* __restrict__ w2t, u16* __restrict__ w3t) {
  int e = blockIdx.x * 256 + threadIdx.x;          // 0 .. 212991
  if (e < 131072) {
    int h = e >> 9, f = e & 511;
    w1t[e] = f2bf(W1[f * 256 + h]);
  } else if (e < 196608) {
    int x = e - 131072;
    int n = x >> 8, k = x & 255;
    w2t[x] = f2bf(W2[k * 256 + n]);
  } else if (e < 212992) {
    int x = e - 196608;
    int n = x >> 8, k = x & 255;
    w3t[x] = f2bf(W3[k * 64 + n]);
  }
}

// ================= fully-fused MLP: lg = relu(relu(X@W1)@W2) @ W3 =================
// 1024 blocks of 64 rows. h1 stripe lives in LDS (XOR-swizzled, we control both
// sides -> rule #21 satisfied: swizzle write AND read, no global_load_lds on it).
// Phase 1: h1s = relu(X@W1)  (A reg-staged fp32->bf16, B via gload_lds)
// Phase 2: acc2 = h1s @ W2   (A from swizzled LDS, B via gload_lds)
// Phase 3: lg  = relu(acc2) @ W3 via quad/w3s swizzled LDS bounce (R7-verified)
__global__ __launch_bounds__(256, 2) void mlp_kernel(const float* __restrict__ X,
                                                     const u16* __restrict__ W1t,
                                                     const u16* __restrict__ W2t,
                                                     const u16* __restrict__ W3t,
                                                     float* __restrict__ lg) {
  __shared__ alignas(16) char smem[69632];
  u16* As   = (u16*)smem;                 // [64][32]   4 KB
  u16* Bs   = (u16*)(smem + 4096);        // [256][32] 16 KB
  u16* h1s  = (u16*)(smem + 20480);       // [64][256] 32 KB, elem-idx ^ ((row&7)<<3)
  u16* quad = (u16*)(smem + 53248);       // [64][64]   8 KB, swizzled
  u16* w3s  = (u16*)(smem + 61440);       // [64][64]   8 KB, swizzled
  const int bm = blockIdx.x, t = threadIdx.x;
  const int wid = t >> 6, lane = t & 63;
  const int wr = wid >> 1, wc = wid & 1;
  const int l15 = lane & 15, lk = lane >> 4;
  const f32x4 z = {0.f, 0.f, 0.f, 0.f};

  // ---- phase 1: h1s = relu(X[bm stripe] @ W1) ----
  {
    f32x4 acc[2][8];
#pragma unroll
    for (int i = 0; i < 2; ++i)
#pragma unroll
      for (int j = 0; j < 8; ++j) acc[i][j] = z;

    for (int k0 = 0; k0 < 512; k0 += 32) {
#pragma unroll
      for (int it = 0; it < 4; ++it) {          // W1 tile [256][32]
        int s = it * 256 + t;
        gload_lds16(W1t + (size_t)(s >> 2) * 512 + k0 + (s & 3) * 8,
                    &Bs[(it * 256 + wid * 64) * 8]);
      }
      {                                          // X tile [64][32] fp32->bf16
        const float* src = X + (size_t)(bm * 64 + (t >> 2)) * 512 + k0 + (t & 3) * 8;
        float4 v0 = *(const float4*)src;
        float4 v1 = *(const float4*)(src + 4);
        bf16x8 wv;
        wv[0] = (__bf16)v0.x; wv[1] = (__bf16)v0.y; wv[2] = (__bf16)v0.z; wv[3] = (__bf16)v0.w;
        wv[4] = (__bf16)v1.x; wv[5] = (__bf16)v1.y; wv[6] = (__bf16)v1.z; wv[7] = (__bf16)v1.w;
        *(bf16x8*)&As[t * 8] = wv;
      }
      __syncthreads();
      bf16x8 af[2], bfr[8];
#pragma unroll
      for (int i = 0; i < 2; ++i)
        af[i] = *(const bf16x8*)&As[(wr * 32 + i * 16 + l15) * 32 + lk * 8];
#pragma unroll
      for (int j = 0; j < 8; ++j)
        bfr[j] = *(const bf16x8*)&Bs[(wc * 128 + j * 16 + l15) * 32 + lk * 8];
#pragma unroll
      for (int i = 0; i < 2; ++i)
#pragma unroll
        for (int j = 0; j < 8; ++j)
          acc[i][j] = __builtin_amdgcn_mfma_f32_16x16x32_bf16(af[i], bfr[j], acc[i][j], 0, 0, 0);
      __syncthreads();
    }
    // epilogue -> swizzled h1s (2-way conflict max)
#pragma unroll
    for (int i = 0; i < 2; ++i)
#pragma unroll
      for (int j = 0; j < 8; ++j)
#pragma unroll
        for (int r = 0; r < 4; ++r) {
          int row = wr * 32 + i * 16 + lk * 4 + r;
          int col = wc * 128 + j * 16 + l15;
          h1s[(row * 256 + col) ^ ((row & 7) << 3)] = f2bf(fmaxf(acc[i][j][r], 0.f));
        }
    __syncthreads();
  }

  // ---- phase 2: acc2 = h1s @ W2 (pre-relu h2 in regs) ----
  f32x4 acc2[2][8];
#pragma unroll
  for (int i = 0; i < 2; ++i)
#pragma unroll
    for (int j = 0; j < 8; ++j) acc2[i][j] = z;

  for (int k0 = 0; k0 < 256; k0 += 32) {
#pragma unroll
    for (int it = 0; it < 4; ++it) {            // W2 tile [256][32]
      int s = it * 256 + t;
      gload_lds16(W2t + (size_t)(s >> 2) * 256 + k0 + (s & 3) * 8,
                  &Bs[(it * 256 + wid * 64) * 8]);
    }
    __syncthreads();
    bf16x8 af[2], bfr[8];
#pragma unroll
    for (int i = 0; i < 2; ++i) {
      int row = wr * 32 + i * 16 + l15;
      af[i] = *(const bf16x8*)&h1s[(row * 256 + k0 + lk * 8) ^ ((row & 7) << 3)];
    }
#pragma unroll
    for (int j = 0; j < 8; ++j)
      bfr[j] = *(const bf16x8*)&Bs[(wc * 128 + j * 16 + l15) * 32 + lk * 8];
#pragma unroll
    for (int i = 0; i < 2; ++i)
#pragma unroll
      for (int j = 0; j < 8; ++j)
        acc2[i][j] = __builtin_amdgcn_mfma_f32_16x16x32_bf16(af[i], bfr[j], acc2[i][j], 0, 0, 0);
    __syncthreads();
  }

  // ---- phase 3: lg = relu(acc2) @ W3 via swizzled LDS bounce ----
  f32x4 acc3[4];
#pragma unroll
  for (int j = 0; j < 4; ++j) acc3[j] = z;

#pragma unroll
  for (int kk = 0; kk < 4; ++kk) {
    if (wc == (kk >> 1)) {                      // owner waves dump relu'd quadrant
#pragma unroll
      for (int i = 0; i < 2; ++i)
#pragma unroll
        for (int j4 = 0; j4 < 4; ++j4) {
          int j = (kk & 1) * 4 + j4;
#pragma unroll
          for (int r = 0; r < 4; ++r) {
            int row = wr * 32 + i * 16 + lk * 4 + r;
            int c   = j4 * 16 + l15;
            quad[(row * 64 + c) ^ ((row & 7) << 3)] = f2bf(fmaxf(acc2[i][j][r], 0.f));
          }
        }
    }
    // W3 chunk [64 cols][64 k], pre-swizzled SOURCE (gload dst is linear)
#pragma unroll
    for (int it = 0; it < 2; ++it) {
      int s = it * 256 + t;
      int col = s >> 3;
      int koff = ((s ^ (col & 7)) & 7) * 8;
      gload_lds16(W3t + (size_t)col * 256 + kk * 64 + koff, &w3s[(it * 256 + wid * 64) * 8]);
    }
    __syncthreads();
    bf16x8 af2, bfr2[4];
#pragma unroll
    for (int ks = 0; ks < 2; ++ks) {
#pragma unroll
      for (int j2 = 0; j2 < 4; ++j2) {
        int col = j2 * 16 + l15;
        bfr2[j2] = *(const bf16x8*)&w3s[(col * 64 + ks * 32 + lk * 8) ^ ((col & 7) << 3)];
      }
      {
        int row = wid * 16 + l15;
        af2 = *(const bf16x8*)&quad[(row * 64 + ks * 32 + lk * 8) ^ ((row & 7) << 3)];
      }
#pragma unroll
      for (int j2 = 0; j2 < 4; ++j2)
        acc3[j2] = __builtin_amdgcn_mfma_f32_16x16x32_bf16(af2, bfr2[j2], acc3[j2], 0, 0, 0);
    }
    __syncthreads();
  }

  // epilogue: wave wid owns rows wid*16..+16, cols 0..63
#pragma unroll
  for (int j2 = 0; j2 < 4; ++j2) {
    int col = j2 * 16 + l15;
#pragma unroll
    for (int r = 0; r < 4; ++r) {
      int row = wid * 16 + lk * 4 + r;
      lg[(size_t)(bm * 64 + row) * 64 + col] = acc3[j2][r];
    }
  }
}

// ================= fused topk + soft-k-medoid per ppr row =================
// 2048 blocks. Phase 1: 2-deep pipelined scan, static-threshold compact
// (uniform [0,1): 32nd of 65536 ~0.9995; T0=0.997 -> ~196 cands, cap 1024,
// P(overflow) ~ e^-400; exact global fallback guards both <32 and overflow).
// Phase 2: wave0 extracts top-32 (val desc, idx asc == jax.lax.top_k) into LDS.
// Phase 3: all 4 waves run the medoid on the block's own result (no tv/ti/rs
// global round-trip). xk/l2m alias the dead candidate buffers (barrier-fenced).
__global__ __launch_bounds__(256, 4) void topk_medoid(const float* __restrict__ ppr,
                                                      const float* __restrict__ lg,
                                                      float* __restrict__ out) {
  __shared__ alignas(16) char smem[13312];
  float* cvals   = (float*)smem;              // [1024] (phase 1-2)
  int*   cidx    = (int*)(smem + 4096);       // [1024] (phase 1-2)
  float* xk      = (float*)smem;              // [32][65] = 8320 B (phase 3, aliases cvals/cidx)
  float* l2m     = (float*)(smem + 8448);     // [32][33] = 4224 B (phase 3)
  float* vals    = (float*)(smem + 12672);    // [32]
  int*   idxs    = (int*)(smem + 12800);      // [32] (also fallback's sel)
  float* dist    = (float*)(smem + 12928);    // [32]
  float* wgt     = (float*)(smem + 13056);    // [32]
  float* partial = (float*)(smem + 13184);    // [4]
  int*   cnt     = (int*)(smem + 13200);      // [1]
  float* rsum    = (float*)(smem + 13204);    // [1]

  const int b = blockIdx.x, t = threadIdx.x;
  const int lane = t & 63, wid = t >> 6;
  const float* row = ppr + (size_t)b * 65536;
  const float4* rp = (const float4*)row;
  const float T0 = 0.997f;

  if (t == 0) *cnt = 0;
  __syncthreads();

  // ---- phase 1: scan ----
  float sum = 0.f;
  float4 c0 = rp[t], c1 = rp[t + 256], c2 = rp[t + 512], c3 = rp[t + 768];

  auto consume = [&](int it) {
    float4 cs[4] = {c0, c1, c2, c3};
#pragma unroll
    for (int q = 0; q < 4; ++q) {
      float4 v = cs[q];
      sum += (v.x + v.y) + (v.z + v.w);
      float mx = fmaxf(fmaxf(v.x, v.y), fmaxf(v.z, v.w));
      if (mx > T0) {
        int fb = (it * 1024 + q * 256 + t) * 4;
        float xs[4] = {v.x, v.y, v.z, v.w};
#pragma unroll
        for (int j = 0; j < 4; ++j) {
          if (xs[j] > T0) {
            int p = atomicAdd(cnt, 1);
            if (p < 1024) { cvals[p] = xs[j]; cidx[p] = fb + j; }
          }
        }
      }
    }
  };

  for (int it = 0; it < 15; ++it) {
    int nb = (it + 1) * 1024 + t;
    float4 n0 = rp[nb], n1 = rp[nb + 256], n2 = rp[nb + 512], n3 = rp[nb + 768];
    consume(it);
    c0 = n0; c1 = n1; c2 = n2; c3 = n3;
  }
  consume(15);

#pragma unroll
  for (int off = 32; off > 0; off >>= 1) sum += __shfl_down(sum, off);
  if (lane == 0) partial[wid] = sum;
  __syncthreads();

  // ---- phase 2: wave0 extraction ----
  if (wid == 0) {
    if (lane == 0) *rsum = partial[0] + partial[1] + partial[2] + partial[3];
    const int ncand = *cnt;
    const int n = ncand < 1024 ? ncand : 1024;
    if (n >= 32 && ncand <= 1024) {
      for (int r = 0; r < 32; ++r) {
        float bv = -__builtin_inff();
        int bi = 0x7fffffff, bp = -1;
        for (int p = lane; p < n; p += 64) {
          float xv = cvals[p];
          int xi = cidx[p];
          if (xv > bv || (xv == bv && xi < bi)) { bv = xv; bi = xi; bp = p; }
        }
#pragma unroll
        for (int off = 32; off > 0; off >>= 1) {
          float ov = __shfl_down(bv, off);
          int   oi = __shfl_down(bi, off);
          int   op = __shfl_down(bp, off);
          if (ov > bv || (ov == bv && oi < bi)) { bv = ov; bi = oi; bp = op; }
        }
        if (lane == 0) {
          vals[r] = bv; idxs[r] = bi;
          if (bp >= 0) { cvals[bp] = -__builtin_inff(); cidx[bp] = 0x7fffffff; }
        }
      }
    } else {
      // exact fallback: 32 rounds of global argmax with exclusion
      for (int r = 0; r < 32; ++r) {
        float bv = -__builtin_inff();
        int bi = 0x7fffffff;
        for (int p = lane; p < 65536; p += 64) {
          float xv = row[p];
          bool skip = false;
          for (int q = 0; q < r; ++q) skip = skip || (idxs[q] == p);
          if (!skip && (xv > bv || (xv == bv && p < bi))) { bv = xv; bi = p; }
        }
#pragma unroll
        for (int off = 32; off > 0; off >>= 1) {
          float ov = __shfl_down(bv, off);
          int   oi = __shfl_down(bi, off);
          if (ov > bv || (ov == bv && oi < bi)) { bv = ov; bi = oi; }
        }
        if (lane == 0) { vals[r] = bv; idxs[r] = bi; }
      }
    }
  }
  __syncthreads();

  // ---- phase 3: medoid on own result ----
  const float rs_b = *rsum;
#pragma unroll
  for (int j = 0; j < 8; ++j) {
    int s = j * 256 + t;
    int r = s >> 6, c = s & 63;
    xk[r * 65 + c] = lg[(size_t)idxs[r] * 64 + c];
  }
  __syncthreads();
#pragma unroll
  for (int j = 0; j < 4; ++j) {
    int p = j * 256 + t;
    int c = p >> 5, m = p & 31;
    float d = 0.f;
#pragma unroll
    for (int ch = 0; ch < 64; ++ch) {
      float df = xk[c * 65 + ch] - xk[m * 65 + ch];
      d += df * df;
    }
    l2m[c * 33 + m] = sqrtf(d + 1e-12f);
  }
  __syncthreads();
  if (t < 32) {
    float d = 0.f;
#pragma unroll
    for (int m = 0; m < 32; ++m) d += vals[m] * l2m[t * 33 + m];
    if (vals[t] == 0.f) d = 3.402823466e+38f;
    dist[t] = d;
  }
  __syncthreads();
  if (t == 0) {
    float mx = -3.402823466e+38f;
    for (int c = 0; c < 32; ++c) mx = fmaxf(mx, -dist[c]);
    float s = 0.f;
    for (int c = 0; c < 32; ++c) { float e = expf(-dist[c] - mx); wgt[c] = e; s += e; }
    float s2 = 0.f;
    for (int c = 0; c < 32; ++c) { wgt[c] = wgt[c] / s * vals[c]; s2 += wgt[c]; }
    float inv = 1.f / s2;
    for (int c = 0; c < 32; ++c) wgt[c] *= inv;
  }
  __syncthreads();
  if (t < 64) {
    float o = 0.f;
#pragma unroll
    for (int k = 0; k < 32; ++k) o += wgt[k] * xk[k * 65 + t];
    out[(size_t)b * 64 + t] = rs_b * o;
  }
}

// ---------------- launch ----------------
extern "C" void kernel_launch(void* const* d_in, const int* in_sizes, int n_in,
                              void* d_out, int out_size, void* d_ws, size_t ws_size,
                              hipStream_t stream) {
  const float* X   = (const float*)d_in[0];
  const float* ppr = (const float*)d_in[1];
  const float* W1  = (const float*)d_in[2];
  const float* W2  = (const float*)d_in[3];
  const float* W3  = (const float*)d_in[4];
  float* out = (float*)d_out;
  char* ws = (char*)d_ws;

  u16*  w1t = (u16*)(ws + 0);                    // 256x512 bf16
  u16*  w2t = (u16*)(ws + 262144);               // 256x256 bf16
  u16*  w3t = (u16*)(ws + 393216);               // 64x256 bf16
  float* lg = (float*)(ws + 458752);             // 65536x64 fp32

  (void)in_sizes; (void)n_in; (void)out_size; (void)ws_size;

  conv_weights<<<832, 256, 0, stream>>>(W1, W2, W3, w1t, w2t, w3t);
  mlp_kernel<<<1024, 256, 0, stream>>>(X, w1t, w2t, w3t, lg);
  topk_medoid<<<2048, 256, 0, stream>>>(ppr, lg, out);
}